// Round 5
// baseline (494.201 us; speedup 1.0000x reference)
//
#include <hip/hip_runtime.h>
#include <stdint.h>

// Problem constants (fixed by reference): T=512, B=256, H=256, 3H=768.
// Pipeline (R5 = R4 + the missing post-init barrier in gru_scan):
//   prep_weights: Wi,Wh (fp32 [256][768]) -> WiT,WhT (bf16 [768][256]).
//   gi_gemm:      BARRIER-FREE main loop. Each lane loads its own 256 B of the
//                 A-chunk directly from global (L1-shared across waves) -> no LDS
//                 A-tile, no per-chunk __syncthreads, no vmcnt(0) drains. r/z-gate
//                 Wi frags in regs (128 VGPR); n-gate WinT (128 KB) in swizzled LDS.
//   gru_scan:     reset-segment-parallel scan, 16 slots/wg, single barrier/iter.
//                 r/z-gate Wh frags in regs (128 VGPR); n-gate WhnT (128 KB) in
//                 swizzled LDS shared by all waves (fixes the 192-reg overflow
//                 that forced in-loop weight reloads at VGPR_Count=128 in R0-R3).
//                 GI read per-lane directly (packed uints, per-quad-uniform row),
//                 double-register prefetched one iteration ahead.
//                 R4 BUG FIX: __syncthreads() after s_h[0] init -- R4 dropped it
//                 with the s_gi prologue, racing wave A's first MFMA read of
//                 s_h[0] against wave B's init write (absmax 0.73).
// GI layout: t-major packed pairs. uint idx ((t*256+b)*384 + g*128 + wv*16+n16)
//   = {lo: col wv*32+n16, hi: col wv*32+16+n16} of gate g.
// LDS WnT swizzle: row c (512 B) = 32 granules of 16 B; granule g stored at
//   position g ^ (c&7); read granule (kt*4+quad) ^ (n16&7) (c&7 == n16&7 since
//   wv*32 = 0 mod 8). XOR involution -> write/read agree; b128 reads balanced
//   across the 8 granule-classes.
// MFMA 16x16x32 bf16 layouts (HW-verified):
//   A[m=lane&15][k=quad*8+j], B[k=quad*8+j][n=lane&15], C/D[row=quad*4+reg][col=lane&15]

typedef __attribute__((ext_vector_type(8))) __bf16 bf16x8;
typedef __attribute__((ext_vector_type(4))) float f32x4;

__device__ __forceinline__ float bf2f(unsigned short u) {
    union { unsigned int i; float f; } v; v.i = ((unsigned int)u) << 16; return v.f;
}
__device__ __forceinline__ unsigned short f2bf(float f) {
    union { float f; unsigned int i; } v; v.f = f;
    unsigned int x = v.i;
    x = x + 0x7fffu + ((x >> 16) & 1u);   // RNE
    return (unsigned short)(x >> 16);
}
__device__ __forceinline__ float fsig(float x) {
    return __builtin_amdgcn_rcpf(1.f + __builtin_amdgcn_exp2f(-1.442695041f * x));
}
__device__ __forceinline__ float ftanh(float x) {
    return 1.f - 2.f * __builtin_amdgcn_rcpf(1.f + __builtin_amdgcn_exp2f(2.885390082f * x));
}

// ---------------------------------------------------------------- prep
__global__ void prep_weights(const float* __restrict__ Wi, const float* __restrict__ Wh,
                             unsigned short* __restrict__ WiT, unsigned short* __restrict__ WhT) {
    const int idx = blockIdx.x * 256 + threadIdx.x;          // [0, 196608)
    const float* src = blockIdx.y ? Wh : Wi;
    unsigned short* dst = blockIdx.y ? WhT : WiT;
    const int c = idx >> 8, k = idx & 255;
    dst[c * 256 + k] = f2bf(src[k * 768 + c]);
}

// stage n-gate weight matrix WnT (rows 512..767 of WT) into swizzled LDS.
// 8192 granules of 16 B; 512 threads x 16 granules, coalesced source.
__device__ __forceinline__ void stage_wn(const unsigned short* __restrict__ WT,
                                         unsigned short* __restrict__ s_wn, int tid) {
#pragma unroll
    for (int w = 0; w < 16; ++w) {
        const int gi = tid + w * 512;
        const int c = gi >> 5, gr = gi & 31;
        bf16x8 v = *(const bf16x8*)(WT + (size_t)(512 + c) * 256 + gr * 8);
        *(bf16x8*)(&s_wn[(c * 32 + (gr ^ (c & 7))) * 8]) = v;
    }
}

// ---------------------------------------------------------------- kernel 1: GI = ins@Wi + bi
// Barrier-free: 256 wgs x 512 thr, 32 chunks of 16 t-major rows each; lane
// (n16,quad) loads row n16's cols [kt*32+quad*8, +8) directly (L1-shared).
__launch_bounds__(512, 2)
__global__ void gi_gemm(const float* __restrict__ ins, const unsigned short* __restrict__ WiT,
                        const float* __restrict__ bi, unsigned int* __restrict__ GI32) {
    __shared__ unsigned short s_wn[65536];          // 128 KB: WinT swizzled

    const int tid = threadIdx.x;
    const int lane = tid & 63, wv = tid >> 6;       // 8 waves
    const int quad = lane >> 4, n16 = lane & 15;

    stage_wn(WiT, s_wn, tid);

    // r,z-gate Wi B-fragments in registers (32 frags = 128 VGPR)
    bf16x8 wfrag[2][2][8];
#pragma unroll
    for (int g = 0; g < 2; ++g)
#pragma unroll
        for (int tl = 0; tl < 2; ++tl) {
            const int c = g * 256 + wv * 32 + tl * 16 + n16;
            const unsigned short* src = WiT + c * 256 + quad * 8;
#pragma unroll
            for (int kt = 0; kt < 8; ++kt)
                wfrag[g][tl][kt] = *(const bf16x8*)(src + kt * 32);
        }
    float bi_r[3][2];
#pragma unroll
    for (int g = 0; g < 3; ++g)
#pragma unroll
        for (int tl = 0; tl < 2; ++tl)
            bi_r[g][tl] = bi[g * 256 + wv * 32 + tl * 16 + n16];

    const int key = n16 & 7;                         // swizzle key (c&7, same for both tl)
    const int c0row = (wv * 32 + n16) * 32;          // granule-row base, tl=0
    const int c1row = (wv * 32 + 16 + n16) * 32;     // tl=1

    __syncthreads();   // s_wn ready; ONLY barrier in the kernel

    for (int i = 0; i < 32; ++i) {
        const int chunk = blockIdx.x + i * 256;      // 16 consecutive t-major rows
        // A-fragments: direct per-lane loads (row n16 of the chunk)
        const float* arow = ins + ((size_t)chunk * 16 + n16) * 256 + quad * 8;
        bf16x8 af[8];
#pragma unroll
        for (int kt = 0; kt < 8; ++kt) {
            const float4 q0 = *(const float4*)(arow + kt * 32);
            const float4 q1 = *(const float4*)(arow + kt * 32 + 4);
            bf16x8 v;
            v[0] = (__bf16)q0.x; v[1] = (__bf16)q0.y; v[2] = (__bf16)q0.z; v[3] = (__bf16)q0.w;
            v[4] = (__bf16)q1.x; v[5] = (__bf16)q1.y; v[6] = (__bf16)q1.z; v[7] = (__bf16)q1.w;
            af[kt] = v;
        }

        f32x4 acc[3][2] = {};
#pragma unroll
        for (int kt = 0; kt < 8; ++kt) {
#pragma unroll
            for (int g = 0; g < 2; ++g)
#pragma unroll
                for (int tl = 0; tl < 2; ++tl)
                    acc[g][tl] = __builtin_amdgcn_mfma_f32_16x16x32_bf16(af[kt], wfrag[g][tl][kt], acc[g][tl], 0, 0, 0);
            const int gsw = ((kt * 4 + quad) ^ key) * 8;
            const bf16x8 bn0 = *(const bf16x8*)(&s_wn[(c0row * 8) + gsw]);
            const bf16x8 bn1 = *(const bf16x8*)(&s_wn[(c1row * 8) + gsw]);
            acc[2][0] = __builtin_amdgcn_mfma_f32_16x16x32_bf16(af[kt], bn0, acc[2][0], 0, 0, 0);
            acc[2][1] = __builtin_amdgcn_mfma_f32_16x16x32_bf16(af[kt], bn1, acc[2][1], 0, 0, 0);
        }

        // packed epilogue (R3-verified): 16 consecutive GI rows, full lines
        {
            const int t = chunk >> 4;
            const int b0 = (chunk & 15) * 16;
#pragma unroll
            for (int g = 0; g < 3; ++g)
#pragma unroll
                for (int r = 0; r < 4; ++r) {
                    const unsigned int lo = f2bf(acc[g][0][r] + bi_r[g][0]);
                    const unsigned int hi = f2bf(acc[g][1][r] + bi_r[g][1]);
                    GI32[((size_t)t * 256 + b0 + quad * 4 + r) * 384 + g * 128 + wv * 16 + n16] =
                        lo | (hi << 16);
                }
        }
    }
}

// ---------------------------------------------------------------- kernel 2: segment-parallel GRU scan
// slot = quad*4+r owns window [slot*32, slot*32+32); processes [start,end]
// consecutively. t_cur[r] is uniform within a quad -> per-lane direct GI loads.
__launch_bounds__(512, 2)
__global__ void gru_scan(const unsigned short* __restrict__ GI, const int* __restrict__ resets,
                         const float* __restrict__ carry, const unsigned short* __restrict__ WhT,
                         const float* __restrict__ bhn, float* __restrict__ out) {
    __shared__ int s_reset[512];                    //   2,048 B
    __shared__ unsigned short s_h[2][16 * 264];     //  16,896 B (h bf16, A-operand, dbuf)
    __shared__ unsigned short s_wn[65536];          // 131,072 B: WhnT swizzled (shared by all waves)

    const int b = blockIdx.x;
    const int tid = threadIdx.x;
    const int lane = tid & 63, wv = tid >> 6;
    const int quad = lane >> 4, n16 = lane & 15;

    s_reset[tid] = resets[tid * 256 + b];
    stage_wn(WhT, s_wn, tid);

    // r,z-gate Wh B-fragments in registers (32 frags = 128 VGPR)
    bf16x8 wfrag[2][2][8];
#pragma unroll
    for (int g = 0; g < 2; ++g)
#pragma unroll
        for (int tl = 0; tl < 2; ++tl) {
            const int c = g * 256 + wv * 32 + tl * 16 + n16;
            const unsigned short* src = WhT + c * 256 + quad * 8;
#pragma unroll
            for (int kt = 0; kt < 8; ++kt)
                wfrag[g][tl][kt] = *(const bf16x8*)(src + kt * 32);
        }
    float bhn_r[2];
    bhn_r[0] = bhn[wv * 32 + n16];
    bhn_r[1] = bhn[wv * 32 + 16 + n16];

    const int key = n16 & 7;
    const int c0row = (wv * 32 + n16) * 32;
    const int c1row = (wv * 32 + 16 + n16) * 32;

    __syncthreads();   // s_reset + s_wn visible

    // per-slot [start, end] from the reset pattern (verified logic)
    int t_cur[4], t_end[4];
    float h_prev[2][4];
#pragma unroll
    for (int r = 0; r < 4; ++r) {
        const int slot = quad * 4 + r;
        const int w0 = slot * 32;
        int st = -1;
        for (int t = w0; t < w0 + 32; ++t)
            if (t == 0 || s_reset[t] != 0) { st = t; break; }
        int en = 511;
        for (int t = w0 + 32; t < 512; ++t)
            if (s_reset[t] != 0) { en = t - 1; break; }
        float h0 = 0.f, h1 = 0.f;
        if (st == 0 && s_reset[0] == 0) {   // faithful: initial carry when t=0 not reset
            h0 = carry[b * 256 + wv * 32 + n16];
            h1 = carry[b * 256 + wv * 32 + 16 + n16];
        }
        if (st < 0) { t_cur[r] = 1; t_end[r] = 0; }   // dead slot
        else        { t_cur[r] = st; t_end[r] = en; }
        h_prev[0][r] = h0; h_prev[1][r] = h1;
        s_h[0][slot * 264 + wv * 32 + n16] = f2bf(h0);
        s_h[0][slot * 264 + wv * 32 + 16 + n16] = f2bf(h1);
    }

    // direct GI access: lane's 3 packed uints per slot-row (t_cur uniform per quad)
    const unsigned int* GI32b = (const unsigned int*)GI + (size_t)b * 384 + (wv * 16 + n16);
    unsigned int gva[4][3], gvb[4][3];
#pragma unroll
    for (int r = 0; r < 4; ++r) {
        const int tr0 = (t_cur[r] <= t_end[r]) ? t_cur[r] : 0;
        const unsigned int* gp = GI32b + (size_t)tr0 * 98304;
        gva[r][0] = gp[0]; gva[r][1] = gp[128]; gva[r][2] = gp[256];
    }

    __syncthreads();   // R4 BUG FIX: s_h[0] init (all waves' columns) must be
                       // visible before the first MFMA read of s_h[0].

#define SCAN_STEP(GCUR, GNXT)                                                                   \
    {                                                                                           \
        const bool any_ = (t_cur[0] <= t_end[0]) | (t_cur[1] <= t_end[1]) |                     \
                          (t_cur[2] <= t_end[2]) | (t_cur[3] <= t_end[3]);                      \
        if (__ballot((int)any_) == 0ull) break;                                                 \
        /* A) prefetch next-iteration GI rows (t+1) -> registers */                             \
        _Pragma("unroll")                                                                       \
        for (int r = 0; r < 4; ++r) {                                                           \
            const int trn = (t_cur[r] < t_end[r]) ? (t_cur[r] + 1) : 0;                         \
            const unsigned int* gp = GI32b + (size_t)trn * 98304;                               \
            GNXT[r][0] = gp[0]; GNXT[r][1] = gp[128]; GNXT[r][2] = gp[256];                     \
        }                                                                                       \
        /* B) gh = h @ Wh for all 16 slots */                                                   \
        f32x4 acc2[3][2] = {};                                                                  \
        _Pragma("unroll")                                                                       \
        for (int kt = 0; kt < 8; ++kt) {                                                        \
            bf16x8 af = *(const bf16x8*)(&s_h[buf][n16 * 264 + kt * 32 + quad * 8]);            \
            _Pragma("unroll")                                                                   \
            for (int g = 0; g < 2; ++g)                                                         \
                _Pragma("unroll")                                                               \
                for (int tl = 0; tl < 2; ++tl)                                                  \
                    acc2[g][tl] = __builtin_amdgcn_mfma_f32_16x16x32_bf16(af, wfrag[g][tl][kt], acc2[g][tl], 0, 0, 0); \
            const int gsw = ((kt * 4 + quad) ^ key) * 8;                                        \
            const bf16x8 bn0 = *(const bf16x8*)(&s_wn[(c0row * 8) + gsw]);                      \
            const bf16x8 bn1 = *(const bf16x8*)(&s_wn[(c1row * 8) + gsw]);                      \
            acc2[2][0] = __builtin_amdgcn_mfma_f32_16x16x32_bf16(af, bn0, acc2[2][0], 0, 0, 0); \
            acc2[2][1] = __builtin_amdgcn_mfma_f32_16x16x32_bf16(af, bn1, acc2[2][1], 0, 0, 0); \
        }                                                                                       \
        /* C) gates + h update + output */                                                      \
        float hn[2][4];                                                                         \
        _Pragma("unroll")                                                                       \
        for (int r = 0; r < 4; ++r) {                                                           \
            const bool alive = t_cur[r] <= t_end[r];                                            \
            const unsigned int ur = GCUR[r][0], uz = GCUR[r][1], un = GCUR[r][2];               \
            _Pragma("unroll")                                                                   \
            for (int tl = 0; tl < 2; ++tl) {                                                    \
                const int c = wv * 32 + tl * 16 + n16;                                          \
                const float gr = bf2f((unsigned short)(tl ? (ur >> 16) : (ur & 0xffffu)));      \
                const float gz = bf2f((unsigned short)(tl ? (uz >> 16) : (uz & 0xffffu)));      \
                const float gn = bf2f((unsigned short)(tl ? (un >> 16) : (un & 0xffffu)));      \
                const float rr = fsig(gr + acc2[0][tl][r]);                                     \
                const float zz = fsig(gz + acc2[1][tl][r]);                                     \
                const float nn = ftanh(gn + rr * (acc2[2][tl][r] + bhn_r[tl]));                 \
                hn[tl][r] = (1.f - zz) * nn + zz * h_prev[tl][r];                               \
                if (alive) out[((size_t)t_cur[r] * 256 + b) * 256 + c] = hn[tl][r];             \
            }                                                                                   \
        }                                                                                       \
        /* D) advance + write h for next iteration */                                           \
        _Pragma("unroll")                                                                       \
        for (int r = 0; r < 4; ++r) {                                                           \
            const int slot = quad * 4 + r;                                                      \
            const bool alive = t_cur[r] <= t_end[r];                                            \
            const int tn = t_cur[r] + 1;                                                        \
            const bool nalive = alive && (tn <= t_end[r]);                                      \
            float k0 = 0.f, k1 = 0.f;                                                           \
            if (nalive && s_reset[tn & 511] == 0) { k0 = hn[0][r]; k1 = hn[1][r]; }             \
            h_prev[0][r] = k0; h_prev[1][r] = k1;                                               \
            s_h[buf ^ 1][slot * 264 + wv * 32 + n16] = f2bf(k0);                                \
            s_h[buf ^ 1][slot * 264 + wv * 32 + 16 + n16] = f2bf(k1);                           \
            if (alive) t_cur[r] = tn;                                                           \
        }                                                                                       \
        __syncthreads();   /* single barrier per iteration (s_h dbuf) */                        \
        buf ^= 1;                                                                               \
    }

    int buf = 0;
    for (int it2 = 0; it2 < 260; ++it2) {
        SCAN_STEP(gva, gvb)
        SCAN_STEP(gvb, gva)
    }
#undef SCAN_STEP
}

// ---------------------------------------------------------------- launch
extern "C" void kernel_launch(void* const* d_in, const int* in_sizes, int n_in,
                              void* d_out, int out_size, void* d_ws, size_t ws_size,
                              hipStream_t stream) {
    const float* ins   = (const float*)d_in[0];
    const int* resets  = (const int*)d_in[1];
    const float* carry = (const float*)d_in[2];
    const float* Wi    = (const float*)d_in[3];
    const float* bi    = (const float*)d_in[4];
    const float* Wh    = (const float*)d_in[5];
    const float* bhn   = (const float*)d_in[6];
    float* out = (float*)d_out;

    unsigned short* WiT = (unsigned short*)d_ws;        // [768][256] bf16
    unsigned short* WhT = WiT + 196608;                 // [768][256] bf16
    unsigned short* GI  = WhT + 196608;                 // [512][256][perm 768] bf16 (t-major, packed pairs)

    prep_weights<<<dim3(768, 2), dim3(256), 0, stream>>>(Wi, Wh, WiT, WhT);
    gi_gemm<<<dim3(256), dim3(512), 0, stream>>>(ins, WiT, bi, (unsigned int*)GI);
    gru_scan<<<dim3(256), dim3(512), 0, stream>>>(GI, resets, carry, WhT, bhn, out);
}